// Round 19
// baseline (333.868 us; speedup 1.0000x reference)
//
#include <hip/hip_runtime.h>

#define HW 65536
#define NOUT 81     // 9 mask + 4*18 off
#define NFEAT 192   // 144 patch + 48 passthrough
#define WROW 84     // padded weight row stride

typedef unsigned short ushort_t;
typedef unsigned int uint_t;

__device__ __forceinline__ float bfhi(uint_t u) {   // high ushort IS the f32 pattern
    union { unsigned int i; float f; } v; v.i = u & 0xffff0000u; return v.f;
}
__device__ __forceinline__ float bflo(uint_t u) {
    union { unsigned int i; float f; } v; v.i = u << 16; return v.f;
}
__device__ __forceinline__ ushort_t f2bf(float f) {
    union { float f; unsigned int i; } v; v.f = f;
    unsigned int r = v.i + 0x7FFF + ((v.i >> 16) & 1);   // RNE
    return (ushort_t)(r >> 16);
}

// ---------------------------------------------------------------------------
// Setup: collapse (conv3x3 -> 1x1) into a single 192->81 linear map, padded.
// ---------------------------------------------------------------------------
__global__ __launch_bounds__(256) void setup_weights(
    const float* __restrict__ off_pconv_w,  // (4,16,16,3,3)
    const float* __restrict__ off_w,        // (4,18,64)
    const float* __restrict__ off_b,        // (4,18)
    const float* __restrict__ mask_pconv_w, // (16,16,3,3)
    const float* __restrict__ mask_w,       // (9,64)
    const float* __restrict__ mask_b,       // (9,)
    float* __restrict__ WtP,                // (192,84)
    float* __restrict__ biasP)              // (81,)
{
    int id = blockIdx.x * 256 + threadIdx.x;
    const float PTS[18] = {-1,-1, -1,0, -1,1, 0,-1, 0,0, 0,1, 1,-1, 1,0, 1,1};
    if (id < NFEAT * WROW) {
        int f = id / WROW;
        int o = id % WROW;
        float v = 0.f;
        if (o < NOUT) {
            if (f < 144) {
                int p = f >> 4, c = f & 15;
                float s = 0.f;
                if (o < 9) {
                    for (int cm = 0; cm < 16; ++cm)
                        s += mask_w[o * 64 + cm] * mask_pconv_w[(cm * 16 + c) * 9 + p];
                } else {
                    int oo = o - 9, i = oo / 18, j = oo % 18;
                    for (int cm = 0; cm < 16; ++cm)
                        s += off_w[(i * 18 + j) * 64 + cm] * off_pconv_w[((i * 16 + cm) * 16 + c) * 9 + p];
                }
                v = s;
            } else {
                int c = f - 144;
                if (o < 9) v = mask_w[o * 64 + 16 + c];
                else { int oo = o - 9, i = oo / 18, j = oo % 18; v = off_w[(i * 18 + j) * 64 + 16 + c]; }
            }
        }
        WtP[id] = v;
    } else if (id < NFEAT * WROW + NOUT) {
        int o = id - NFEAT * WROW;
        float v;
        if (o < 9) v = mask_b[o];
        else {
            int oo = o - 9, i = oo / 18, j = oo % 18;
            v = off_b[i * 18 + j] + PTS[j] * (float)(2 * i + 1);
        }
        biasP[o] = v;
    }
}

// ---------------------------------------------------------------------------
// Conv (round-18 verbatim): SGPR weights, c-loop unroll 4.
// ---------------------------------------------------------------------------
__global__ __launch_bounds__(256) void conv_sgpr(
    const float* __restrict__ x, const float* __restrict__ WtP,
    const float* __restrict__ biasP,
    float* __restrict__ mask_ws, float* __restrict__ off_ws)
{
    int tid = threadIdx.x;
    int lane = tid & 63;
    int bid = blockIdx.x;            // 2048
    int b = bid >> 10;
    int pix = (bid & 1023) * 64 + lane;
    int h = pix >> 8, w = pix & 255;

    int ob0 = __builtin_amdgcn_readfirstlane((tid >> 6) * 20);

    float acc[21];
#pragma unroll
    for (int j = 0; j < 21; ++j) acc[j] = biasP[ob0 + j];

    const float* xb = x + (size_t)b * 64 * HW;

#pragma unroll 1
    for (int p = 0; p < 9; ++p) {
        int hh = h + p / 3 - 1;
        int dx = p % 3 - 1;
        int ww = w + dx;
        bool valid = ((unsigned)hh < 256u) && ((unsigned)ww < 256u);
        int poff = hh * 256 + ww;
#pragma unroll 4
        for (int c = 0; c < 16; ++c) {
            float xv = valid ? xb[c * HW + poff] : 0.f;
            const float* wr = WtP + (p * 16 + c) * WROW + ob0;
#pragma unroll
            for (int j = 0; j < 21; ++j) acc[j] = fmaf(xv, wr[j], acc[j]);
        }
    }
#pragma unroll 4
    for (int c = 0; c < 48; ++c) {
        float xv = xb[(16 + c) * HW + pix];
        const float* wr = WtP + (144 + c) * WROW + ob0;
#pragma unroll
        for (int j = 0; j < 21; ++j) acc[j] = fmaf(xv, wr[j], acc[j]);
    }

#pragma unroll
    for (int j = 0; j < 21; ++j) {
        int o = ob0 + j;
        float* pl;
        if (o < 9) pl = mask_ws + (size_t)(b * 9 + o) * HW + pix;
        else       pl = off_ws  + (size_t)(b * 72 + (o - 9)) * HW + pix;
        *pl = acc[j];
    }
}

// ---------------------------------------------------------------------------
// Transpose y -> c4-major interleaved Tc[z][pix][c4:{t0 4ch, t1 4ch}] bf16.
// (round-14 verbatim)
// ---------------------------------------------------------------------------
__global__ __launch_bounds__(256) void transpose_y_c(
    const float* __restrict__ y, ushort_t* __restrict__ Tc)
{
    int bid = blockIdx.x;            // 2048
    int z = bid & 7, pr = bid >> 3;
    int pix = pr * 256 + threadIdx.x;
    int xb = z >> 2, i = z & 3;

    const float* p0 = y + (size_t)(xb * 64 + i * 16) * HW + pix;
    const float* p1 = y + (size_t)((xb + 2) * 64 + i * 16) * HW + pix;

    ushort_t v0[16], v1[16];
#pragma unroll
    for (int c = 0; c < 16; ++c) v0[c] = f2bf(p0[(size_t)c * HW]);
#pragma unroll
    for (int c = 0; c < 16; ++c) v1[c] = f2bf(p1[(size_t)c * HW]);

    uint4* dst = (uint4*)(Tc + ((size_t)z * HW + pix) * 32);
#pragma unroll
    for (int j = 0; j < 4; ++j) {
        ushort_t row[8] = {v0[4*j], v0[4*j+1], v0[4*j+2], v0[4*j+3],
                           v1[4*j], v1[4*j+1], v1[4*j+2], v1[4*j+3]};
        dst[j] = *(const uint4*)row;
    }
}

// ---------------------------------------------------------------------------
// Warp kernel v11: round-17 structure, NT stores reverted to PLAIN stores.
// Rationale: each wave store instr covers 64B (16 px x 4B) = HALF a 128B
// line; NT bypasses L2 so half-lines can't merge with the adjacent wc-tile's
// half before DRAM -> ~2x write inefficiency. Plain stores let L2 coalesce
// full lines; L3 (256MB) still backstops Tc gather re-reads.
// ---------------------------------------------------------------------------
__global__ __launch_bounds__(256) void warp_k(
    const ushort_t* __restrict__ Tc,    // (8,HW,32) bf16 c4-major
    const float* __restrict__ mask_ws,  // (2,9,HW)
    const float* __restrict__ off_ws,   // (2,72,HW)
    float* __restrict__ out)            // (4,64,9,HW)
{
    int bid = blockIdx.x;
    int z  = bid & 7;
    int wc = (bid >> 3) & 3;
    int h  = (bid >> 5) & 255;
    int k  = bid >> 13;              // 0..8
    int c4 = threadIdx.x & 3;
    int pl = threadIdx.x >> 2;       // 0..63
    int w  = wc * 64 + pl;
    int pix = h * 256 + w;
    int xb = z >> 2, i = z & 3;

    const ushort_t* Tt = Tc + (size_t)z * HW * 32;

    float ox = off_ws[(size_t)(z * 18 + 2 * k) * HW + pix];
    float oy = off_ws[(size_t)(z * 18 + 2 * k + 1) * HW + pix];
    float m  = mask_ws[(size_t)(xb * 9 + k) * HW + pix];

    float px = fminf(fmaxf((float)w + ox, 0.f), 255.f);
    float py = fminf(fmaxf((float)h + oy, 0.f), 255.f);
    float x0f = floorf(px), y0f = floorf(py);
    float wx = px - x0f, wy = py - y0f;
    int x0 = (int)x0f, y0 = (int)y0f;
    int x1 = min(x0 + 1, 255), y1 = min(y0 + 1, 255);

    float w00 = (1.f - wx) * (1.f - wy) * m;
    float w01 = wx * (1.f - wy) * m;
    float w10 = (1.f - wx) * wy * m;
    float w11 = wx * wy * m;

    int sec = c4 * 8;
    uint4 A = *(const uint4*)(Tt + (size_t)(y0 * 256 + x0) * 32 + sec);
    uint4 B = *(const uint4*)(Tt + (size_t)(y0 * 256 + x1) * 32 + sec);
    uint4 C = *(const uint4*)(Tt + (size_t)(y1 * 256 + x0) * 32 + sec);
    uint4 D = *(const uint4*)(Tt + (size_t)(y1 * 256 + x1) * 32 + sec);

    float s0 = w00 * bflo(A.x), s1 = w00 * bfhi(A.x);
    float s2 = w00 * bflo(A.y), s3 = w00 * bfhi(A.y);
    float u0 = w00 * bflo(A.z), u1 = w00 * bfhi(A.z);
    float u2 = w00 * bflo(A.w), u3 = w00 * bfhi(A.w);

    s0 = fmaf(w01, bflo(B.x), s0); s1 = fmaf(w01, bfhi(B.x), s1);
    s2 = fmaf(w01, bflo(B.y), s2); s3 = fmaf(w01, bfhi(B.y), s3);
    u0 = fmaf(w01, bflo(B.z), u0); u1 = fmaf(w01, bfhi(B.z), u1);
    u2 = fmaf(w01, bflo(B.w), u2); u3 = fmaf(w01, bfhi(B.w), u3);

    s0 = fmaf(w10, bflo(C.x), s0); s1 = fmaf(w10, bfhi(C.x), s1);
    s2 = fmaf(w10, bflo(C.y), s2); s3 = fmaf(w10, bfhi(C.y), s3);
    u0 = fmaf(w10, bflo(C.z), u0); u1 = fmaf(w10, bfhi(C.z), u1);
    u2 = fmaf(w10, bflo(C.w), u2); u3 = fmaf(w10, bfhi(C.w), u3);

    s0 = fmaf(w11, bflo(D.x), s0); s1 = fmaf(w11, bfhi(D.x), s1);
    s2 = fmaf(w11, bflo(D.y), s2); s3 = fmaf(w11, bfhi(D.y), s3);
    u0 = fmaf(w11, bflo(D.z), u0); u1 = fmaf(w11, bfhi(D.z), u1);
    u2 = fmaf(w11, bflo(D.w), u2); u3 = fmaf(w11, bfhi(D.w), u3);

    float* p0 = out + ((size_t)(xb * 64 + i * 16 + c4 * 4)) * 9 * HW
              + (size_t)k * HW + pix;
    p0[0]               = s0;
    p0[(size_t)9 * HW]  = s1;
    p0[(size_t)18 * HW] = s2;
    p0[(size_t)27 * HW] = s3;
    float* p1 = p0 + (size_t)128 * 9 * HW;
    p1[0]               = u0;
    p1[(size_t)9 * HW]  = u1;
    p1[(size_t)18 * HW] = u2;
    p1[(size_t)27 * HW] = u3;
}

// ---------------------------------------------------------------------------
// Fallback path (ws too small): conv to planes + direct warp from y.
// ---------------------------------------------------------------------------
__global__ __launch_bounds__(256) void warp_apply(
    const float* __restrict__ y,
    const float* __restrict__ mask_ws,
    const float* __restrict__ off_ws,
    float* __restrict__ out)
{
    int w = threadIdx.x;
    int h = blockIdx.x;
    int k = blockIdx.y;
    int z = blockIdx.z;
    int xb = z >> 2, i = z & 3;
    int pix = h * 256 + w;

    float ox = off_ws[(size_t)(z * 18 + 2 * k) * HW + pix];
    float oy = off_ws[(size_t)(z * 18 + 2 * k + 1) * HW + pix];
    float m  = mask_ws[(size_t)(xb * 9 + k) * HW + pix];

    float px = fminf(fmaxf((float)w + ox, 0.f), 255.f);
    float py = fminf(fmaxf((float)h + oy, 0.f), 255.f);
    float x0f = floorf(px), y0f = floorf(py);
    float wx = px - x0f, wy = py - y0f;
    int x0 = (int)x0f, y0 = (int)y0f;
    int x1 = min(x0 + 1, 255), y1 = min(y0 + 1, 255);

    float w00 = (1.f - wx) * (1.f - wy) * m;
    float w01 = wx * (1.f - wy) * m;
    float w10 = (1.f - wx) * wy * m;
    float w11 = wx * wy * m;

    int o00 = y0 * 256 + x0, o01 = y0 * 256 + x1;
    int o10 = y1 * 256 + x0, o11 = y1 * 256 + x1;

    const float* p1 = y + (size_t)(xb * 64 + i * 16) * HW;
    const float* p2 = y + (size_t)((xb + 2) * 64 + i * 16) * HW;
    float* out1 = out + ((size_t)(xb * 64 + i * 16) * 9 + k) * HW + pix;
    float* out2 = out + ((size_t)((xb + 2) * 64 + i * 16) * 9 + k) * HW + pix;

#pragma unroll
    for (int c = 0; c < 16; ++c) {
        const float* q = p1 + (size_t)c * HW;
        float v = w00 * q[o00] + w01 * q[o01] + w10 * q[o10] + w11 * q[o11];
        out1[(size_t)c * 9 * HW] = v;
        q = p2 + (size_t)c * HW;
        v = w00 * q[o00] + w01 * q[o01] + w10 * q[o10] + w11 * q[o11];
        out2[(size_t)c * 9 * HW] = v;
    }
}

// ---------------------------------------------------------------------------
extern "C" void kernel_launch(void* const* d_in, const int* in_sizes, int n_in,
                              void* d_out, int out_size, void* d_ws, size_t ws_size,
                              hipStream_t stream) {
    const float* x            = (const float*)d_in[0];
    const float* y            = (const float*)d_in[1];
    const float* off_pconv_w  = (const float*)d_in[2];
    const float* off_w        = (const float*)d_in[3];
    const float* off_b        = (const float*)d_in[4];
    const float* mask_pconv_w = (const float*)d_in[5];
    const float* mask_w       = (const float*)d_in[6];
    const float* mask_b       = (const float*)d_in[7];
    float* out = (float*)d_out;

    // ws: [WtP 192*84 f32 + biasP: 64KB] [mask (2,9,HW) f32: 4.7MB]
    //     [off (2,72,HW) f32: 37.7MB] [Tc (8,HW,32) bf16: 33.6MB]  ~76MB
    float* WtP     = (float*)d_ws;
    float* biasP   = WtP + NFEAT * WROW;
    float* mask_ws = (float*)((char*)d_ws + 65536);
    float* off_ws  = mask_ws + (size_t)2 * 9 * HW;
    ushort_t* Tc   = (ushort_t*)(off_ws + (size_t)2 * 72 * HW);
    size_t need = 65536 + (size_t)2 * 9 * HW * 4 + (size_t)2 * 72 * HW * 4
                + (size_t)8 * HW * 32 * 2;

    setup_weights<<<64, 256, 0, stream>>>(off_pconv_w, off_w, off_b,
                                          mask_pconv_w, mask_w, mask_b, WtP, biasP);

    conv_sgpr<<<2048, 256, 0, stream>>>(x, WtP, biasP, mask_ws, off_ws);

    if (ws_size >= need) {
        transpose_y_c<<<2048, 256, 0, stream>>>(y, Tc);
        warp_k<<<73728, 256, 0, stream>>>(Tc, mask_ws, off_ws, out);
    } else {
        dim3 g2(256, 9, 8);
        warp_apply<<<g2, 256, 0, stream>>>(y, mask_ws, off_ws, out);
    }
}

// Round 20
// 273.684 us; speedup vs baseline: 1.2199x; 1.2199x over previous
//
#include <hip/hip_runtime.h>

#define HW 65536
#define NOUT 81     // 9 mask + 4*18 off
#define NFEAT 192   // 144 patch + 48 passthrough
#define WROW 84     // padded weight row stride

typedef unsigned short ushort_t;
typedef unsigned int uint_t;

__device__ __forceinline__ float bfhi(uint_t u) {   // high ushort IS the f32 pattern
    union { unsigned int i; float f; } v; v.i = u & 0xffff0000u; return v.f;
}
__device__ __forceinline__ float bflo(uint_t u) {
    union { unsigned int i; float f; } v; v.i = u << 16; return v.f;
}
__device__ __forceinline__ ushort_t f2bf(float f) {
    union { float f; unsigned int i; } v; v.f = f;
    unsigned int r = v.i + 0x7FFF + ((v.i >> 16) & 1);   // RNE
    return (ushort_t)(r >> 16);
}

// ---------------------------------------------------------------------------
// Setup: collapse (conv3x3 -> 1x1) into a single 192->81 linear map, padded.
// ---------------------------------------------------------------------------
__global__ __launch_bounds__(256) void setup_weights(
    const float* __restrict__ off_pconv_w,  // (4,16,16,3,3)
    const float* __restrict__ off_w,        // (4,18,64)
    const float* __restrict__ off_b,        // (4,18)
    const float* __restrict__ mask_pconv_w, // (16,16,3,3)
    const float* __restrict__ mask_w,       // (9,64)
    const float* __restrict__ mask_b,       // (9,)
    float* __restrict__ WtP,                // (192,84)
    float* __restrict__ biasP)              // (81,)
{
    int id = blockIdx.x * 256 + threadIdx.x;
    const float PTS[18] = {-1,-1, -1,0, -1,1, 0,-1, 0,0, 0,1, 1,-1, 1,0, 1,1};
    if (id < NFEAT * WROW) {
        int f = id / WROW;
        int o = id % WROW;
        float v = 0.f;
        if (o < NOUT) {
            if (f < 144) {
                int p = f >> 4, c = f & 15;
                float s = 0.f;
                if (o < 9) {
                    for (int cm = 0; cm < 16; ++cm)
                        s += mask_w[o * 64 + cm] * mask_pconv_w[(cm * 16 + c) * 9 + p];
                } else {
                    int oo = o - 9, i = oo / 18, j = oo % 18;
                    for (int cm = 0; cm < 16; ++cm)
                        s += off_w[(i * 18 + j) * 64 + cm] * off_pconv_w[((i * 16 + cm) * 16 + c) * 9 + p];
                }
                v = s;
            } else {
                int c = f - 144;
                if (o < 9) v = mask_w[o * 64 + 16 + c];
                else { int oo = o - 9, i = oo / 18, j = oo % 18; v = off_w[(i * 18 + j) * 64 + 16 + c]; }
            }
        }
        WtP[id] = v;
    } else if (id < NFEAT * WROW + NOUT) {
        int o = id - NFEAT * WROW;
        float v;
        if (o < 9) v = mask_b[o];
        else {
            int oo = o - 9, i = oo / 18, j = oo % 18;
            v = off_b[i * 18 + j] + PTS[j] * (float)(2 * i + 1);
        }
        biasP[o] = v;
    }
}

// ---------------------------------------------------------------------------
// Conv v4: x staged in LDS (25KB/block: patch window with zero-pad baked in
// + passthrough tile). Kills the 200cy global-load chain (ds_read ~21cy,
// stride-1 conflict-free) and the 4x x-load redundancy across slice waves.
// Weights remain wave-uniform (scalar pipe). Block = 64 px x 4 slice-waves.
// ---------------------------------------------------------------------------
__global__ __launch_bounds__(256) void conv_sgpr(
    const float* __restrict__ x, const float* __restrict__ WtP,
    const float* __restrict__ biasP,
    float* __restrict__ mask_ws, float* __restrict__ off_ws)
{
    __shared__ float XP[16 * 3 * 66];   // 12.7 KB: patch chans, 3 rows, 66 cols
    __shared__ float XQ[48 * 64];       // 12.3 KB: passthrough chans
    int tid = threadIdx.x;
    int bid = blockIdx.x;            // 2048
    int b = bid >> 10;
    int t = bid & 1023;
    int h = t >> 2;
    int w0 = (t & 3) * 64;

    const float* xb = x + (size_t)b * 64 * HW;

    for (int idx = tid; idx < 16 * 3 * 66; idx += 256) {
        int c = idx / 198, rem = idx - c * 198;
        int r = rem / 66, j = rem - r * 66;
        int hh = h + r - 1, ww = w0 - 1 + j;
        float v = 0.f;
        if (((unsigned)hh < 256u) && ((unsigned)ww < 256u))
            v = xb[c * HW + hh * 256 + ww];
        XP[idx] = v;
    }
    for (int idx = tid; idx < 48 * 64; idx += 256) {
        int c = idx >> 6, j = idx & 63;
        XQ[idx] = xb[(16 + c) * HW + h * 256 + w0 + j];
    }
    __syncthreads();

    int lane = tid & 63;
    int ob0 = __builtin_amdgcn_readfirstlane((tid >> 6) * 20);
    int pix = h * 256 + w0 + lane;

    float acc[21];
#pragma unroll
    for (int j = 0; j < 21; ++j) acc[j] = biasP[ob0 + j];

#pragma unroll 1
    for (int p = 0; p < 9; ++p) {
        int r = p / 3, dx = p % 3 - 1;
        const float* xp = &XP[r * 66 + 1 + lane + dx];
#pragma unroll 4
        for (int c = 0; c < 16; ++c) {
            float xv = xp[c * 198];
            const float* wr = WtP + (p * 16 + c) * WROW + ob0;
#pragma unroll
            for (int j = 0; j < 21; ++j) acc[j] = fmaf(xv, wr[j], acc[j]);
        }
    }
#pragma unroll 4
    for (int c = 0; c < 48; ++c) {
        float xv = XQ[c * 64 + lane];
        const float* wr = WtP + (144 + c) * WROW + ob0;
#pragma unroll
        for (int j = 0; j < 21; ++j) acc[j] = fmaf(xv, wr[j], acc[j]);
    }

#pragma unroll
    for (int j = 0; j < 21; ++j) {
        int o = ob0 + j;
        float* pl;
        if (o < 9) pl = mask_ws + (size_t)(b * 9 + o) * HW + pix;
        else       pl = off_ws  + (size_t)(b * 72 + (o - 9)) * HW + pix;
        *pl = acc[j];
    }
}

// ---------------------------------------------------------------------------
// Transpose y -> c4-major interleaved Tc[z][pix][c4:{t0 4ch, t1 4ch}] bf16.
// (round-14 verbatim)
// ---------------------------------------------------------------------------
__global__ __launch_bounds__(256) void transpose_y_c(
    const float* __restrict__ y, ushort_t* __restrict__ Tc)
{
    int bid = blockIdx.x;            // 2048
    int z = bid & 7, pr = bid >> 3;
    int pix = pr * 256 + threadIdx.x;
    int xb = z >> 2, i = z & 3;

    const float* p0 = y + (size_t)(xb * 64 + i * 16) * HW + pix;
    const float* p1 = y + (size_t)((xb + 2) * 64 + i * 16) * HW + pix;

    ushort_t v0[16], v1[16];
#pragma unroll
    for (int c = 0; c < 16; ++c) v0[c] = f2bf(p0[(size_t)c * HW]);
#pragma unroll
    for (int c = 0; c < 16; ++c) v1[c] = f2bf(p1[(size_t)c * HW]);

    uint4* dst = (uint4*)(Tc + ((size_t)z * HW + pix) * 32);
#pragma unroll
    for (int j = 0; j < 4; ++j) {
        ushort_t row[8] = {v0[4*j], v0[4*j+1], v0[4*j+2], v0[4*j+3],
                           v1[4*j], v1[4*j+1], v1[4*j+2], v1[4*j+3]};
        dst[j] = *(const uint4*)row;
    }
}

// ---------------------------------------------------------------------------
// Warp kernel (round-18 verbatim, NT stores): k in grid, one chain/thread.
// NT keeps the 604MB write stream OUT of L2, preserving Tc residency for
// the gathers (r19 A/B: plain stores +63us).
// ---------------------------------------------------------------------------
__global__ __launch_bounds__(256) void warp_k(
    const ushort_t* __restrict__ Tc,    // (8,HW,32) bf16 c4-major
    const float* __restrict__ mask_ws,  // (2,9,HW)
    const float* __restrict__ off_ws,   // (2,72,HW)
    float* __restrict__ out)            // (4,64,9,HW)
{
    int bid = blockIdx.x;
    int z  = bid & 7;
    int wc = (bid >> 3) & 3;
    int h  = (bid >> 5) & 255;
    int k  = bid >> 13;              // 0..8
    int c4 = threadIdx.x & 3;
    int pl = threadIdx.x >> 2;       // 0..63
    int w  = wc * 64 + pl;
    int pix = h * 256 + w;
    int xb = z >> 2, i = z & 3;

    const ushort_t* Tt = Tc + (size_t)z * HW * 32;

    float ox = off_ws[(size_t)(z * 18 + 2 * k) * HW + pix];
    float oy = off_ws[(size_t)(z * 18 + 2 * k + 1) * HW + pix];
    float m  = mask_ws[(size_t)(xb * 9 + k) * HW + pix];

    float px = fminf(fmaxf((float)w + ox, 0.f), 255.f);
    float py = fminf(fmaxf((float)h + oy, 0.f), 255.f);
    float x0f = floorf(px), y0f = floorf(py);
    float wx = px - x0f, wy = py - y0f;
    int x0 = (int)x0f, y0 = (int)y0f;
    int x1 = min(x0 + 1, 255), y1 = min(y0 + 1, 255);

    float w00 = (1.f - wx) * (1.f - wy) * m;
    float w01 = wx * (1.f - wy) * m;
    float w10 = (1.f - wx) * wy * m;
    float w11 = wx * wy * m;

    int sec = c4 * 8;
    uint4 A = *(const uint4*)(Tt + (size_t)(y0 * 256 + x0) * 32 + sec);
    uint4 B = *(const uint4*)(Tt + (size_t)(y0 * 256 + x1) * 32 + sec);
    uint4 C = *(const uint4*)(Tt + (size_t)(y1 * 256 + x0) * 32 + sec);
    uint4 D = *(const uint4*)(Tt + (size_t)(y1 * 256 + x1) * 32 + sec);

    float s0 = w00 * bflo(A.x), s1 = w00 * bfhi(A.x);
    float s2 = w00 * bflo(A.y), s3 = w00 * bfhi(A.y);
    float u0 = w00 * bflo(A.z), u1 = w00 * bfhi(A.z);
    float u2 = w00 * bflo(A.w), u3 = w00 * bfhi(A.w);

    s0 = fmaf(w01, bflo(B.x), s0); s1 = fmaf(w01, bfhi(B.x), s1);
    s2 = fmaf(w01, bflo(B.y), s2); s3 = fmaf(w01, bfhi(B.y), s3);
    u0 = fmaf(w01, bflo(B.z), u0); u1 = fmaf(w01, bfhi(B.z), u1);
    u2 = fmaf(w01, bflo(B.w), u2); u3 = fmaf(w01, bfhi(B.w), u3);

    s0 = fmaf(w10, bflo(C.x), s0); s1 = fmaf(w10, bfhi(C.x), s1);
    s2 = fmaf(w10, bflo(C.y), s2); s3 = fmaf(w10, bfhi(C.y), s3);
    u0 = fmaf(w10, bflo(C.z), u0); u1 = fmaf(w10, bfhi(C.z), u1);
    u2 = fmaf(w10, bflo(C.w), u2); u3 = fmaf(w10, bfhi(C.w), u3);

    s0 = fmaf(w11, bflo(D.x), s0); s1 = fmaf(w11, bfhi(D.x), s1);
    s2 = fmaf(w11, bflo(D.y), s2); s3 = fmaf(w11, bfhi(D.y), s3);
    u0 = fmaf(w11, bflo(D.z), u0); u1 = fmaf(w11, bfhi(D.z), u1);
    u2 = fmaf(w11, bflo(D.w), u2); u3 = fmaf(w11, bfhi(D.w), u3);

    float* p0 = out + ((size_t)(xb * 64 + i * 16 + c4 * 4)) * 9 * HW
              + (size_t)k * HW + pix;
    __builtin_nontemporal_store(s0, p0);
    __builtin_nontemporal_store(s1, p0 + (size_t)9 * HW);
    __builtin_nontemporal_store(s2, p0 + (size_t)18 * HW);
    __builtin_nontemporal_store(s3, p0 + (size_t)27 * HW);
    float* p1 = p0 + (size_t)128 * 9 * HW;
    __builtin_nontemporal_store(u0, p1);
    __builtin_nontemporal_store(u1, p1 + (size_t)9 * HW);
    __builtin_nontemporal_store(u2, p1 + (size_t)18 * HW);
    __builtin_nontemporal_store(u3, p1 + (size_t)27 * HW);
}

// ---------------------------------------------------------------------------
// Fallback path (ws too small): conv to planes + direct warp from y.
// ---------------------------------------------------------------------------
__global__ __launch_bounds__(256) void warp_apply(
    const float* __restrict__ y,
    const float* __restrict__ mask_ws,
    const float* __restrict__ off_ws,
    float* __restrict__ out)
{
    int w = threadIdx.x;
    int h = blockIdx.x;
    int k = blockIdx.y;
    int z = blockIdx.z;
    int xb = z >> 2, i = z & 3;
    int pix = h * 256 + w;

    float ox = off_ws[(size_t)(z * 18 + 2 * k) * HW + pix];
    float oy = off_ws[(size_t)(z * 18 + 2 * k + 1) * HW + pix];
    float m  = mask_ws[(size_t)(xb * 9 + k) * HW + pix];

    float px = fminf(fmaxf((float)w + ox, 0.f), 255.f);
    float py = fminf(fmaxf((float)h + oy, 0.f), 255.f);
    float x0f = floorf(px), y0f = floorf(py);
    float wx = px - x0f, wy = py - y0f;
    int x0 = (int)x0f, y0 = (int)y0f;
    int x1 = min(x0 + 1, 255), y1 = min(y0 + 1, 255);

    float w00 = (1.f - wx) * (1.f - wy) * m;
    float w01 = wx * (1.f - wy) * m;
    float w10 = (1.f - wx) * wy * m;
    float w11 = wx * wy * m;

    int o00 = y0 * 256 + x0, o01 = y0 * 256 + x1;
    int o10 = y1 * 256 + x0, o11 = y1 * 256 + x1;

    const float* p1 = y + (size_t)(xb * 64 + i * 16) * HW;
    const float* p2 = y + (size_t)((xb + 2) * 64 + i * 16) * HW;
    float* out1 = out + ((size_t)(xb * 64 + i * 16) * 9 + k) * HW + pix;
    float* out2 = out + ((size_t)((xb + 2) * 64 + i * 16) * 9 + k) * HW + pix;

#pragma unroll
    for (int c = 0; c < 16; ++c) {
        const float* q = p1 + (size_t)c * HW;
        float v = w00 * q[o00] + w01 * q[o01] + w10 * q[o10] + w11 * q[o11];
        out1[(size_t)c * 9 * HW] = v;
        q = p2 + (size_t)c * HW;
        v = w00 * q[o00] + w01 * q[o01] + w10 * q[o10] + w11 * q[o11];
        out2[(size_t)c * 9 * HW] = v;
    }
}

// ---------------------------------------------------------------------------
extern "C" void kernel_launch(void* const* d_in, const int* in_sizes, int n_in,
                              void* d_out, int out_size, void* d_ws, size_t ws_size,
                              hipStream_t stream) {
    const float* x            = (const float*)d_in[0];
    const float* y            = (const float*)d_in[1];
    const float* off_pconv_w  = (const float*)d_in[2];
    const float* off_w        = (const float*)d_in[3];
    const float* off_b        = (const float*)d_in[4];
    const float* mask_pconv_w = (const float*)d_in[5];
    const float* mask_w       = (const float*)d_in[6];
    const float* mask_b       = (const float*)d_in[7];
    float* out = (float*)d_out;

    // ws: [WtP 192*84 f32 + biasP: 64KB] [mask (2,9,HW) f32: 4.7MB]
    //     [off (2,72,HW) f32: 37.7MB] [Tc (8,HW,32) bf16: 33.6MB]  ~76MB
    float* WtP     = (float*)d_ws;
    float* biasP   = WtP + NFEAT * WROW;
    float* mask_ws = (float*)((char*)d_ws + 65536);
    float* off_ws  = mask_ws + (size_t)2 * 9 * HW;
    ushort_t* Tc   = (ushort_t*)(off_ws + (size_t)2 * 72 * HW);
    size_t need = 65536 + (size_t)2 * 9 * HW * 4 + (size_t)2 * 72 * HW * 4
                + (size_t)8 * HW * 32 * 2;

    setup_weights<<<64, 256, 0, stream>>>(off_pconv_w, off_w, off_b,
                                          mask_pconv_w, mask_w, mask_b, WtP, biasP);

    conv_sgpr<<<2048, 256, 0, stream>>>(x, WtP, biasP, mask_ws, off_ws);

    if (ws_size >= need) {
        transpose_y_c<<<2048, 256, 0, stream>>>(y, Tc);
        warp_k<<<73728, 256, 0, stream>>>(Tc, mask_ws, off_ws, out);
    } else {
        dim3 g2(256, 9, 8);
        warp_apply<<<g2, 256, 0, stream>>>(y, mask_ws, off_ws, out);
    }
}

// Round 21
// 270.567 us; speedup vs baseline: 1.2340x; 1.0115x over previous
//
#include <hip/hip_runtime.h>

#define HW 65536
#define NOUT 81     // 9 mask + 4*18 off
#define NFEAT 192   // 144 patch + 48 passthrough
#define WROW 84     // padded weight row stride

typedef unsigned short ushort_t;
typedef unsigned int uint_t;

__device__ __forceinline__ float bfhi(uint_t u) {   // high ushort IS the f32 pattern
    union { unsigned int i; float f; } v; v.i = u & 0xffff0000u; return v.f;
}
__device__ __forceinline__ float bflo(uint_t u) {
    union { unsigned int i; float f; } v; v.i = u << 16; return v.f;
}
__device__ __forceinline__ ushort_t f2bf(float f) {
    union { float f; unsigned int i; } v; v.f = f;
    unsigned int r = v.i + 0x7FFF + ((v.i >> 16) & 1);   // RNE
    return (ushort_t)(r >> 16);
}

// ---------------------------------------------------------------------------
// Setup: collapse (conv3x3 -> 1x1) into a single 192->81 linear map, padded.
// ---------------------------------------------------------------------------
__global__ __launch_bounds__(256) void setup_weights(
    const float* __restrict__ off_pconv_w,  // (4,16,16,3,3)
    const float* __restrict__ off_w,        // (4,18,64)
    const float* __restrict__ off_b,        // (4,18)
    const float* __restrict__ mask_pconv_w, // (16,16,3,3)
    const float* __restrict__ mask_w,       // (9,64)
    const float* __restrict__ mask_b,       // (9,)
    float* __restrict__ WtP,                // (192,84)
    float* __restrict__ biasP)              // (81,)
{
    int id = blockIdx.x * 256 + threadIdx.x;
    const float PTS[18] = {-1,-1, -1,0, -1,1, 0,-1, 0,0, 0,1, 1,-1, 1,0, 1,1};
    if (id < NFEAT * WROW) {
        int f = id / WROW;
        int o = id % WROW;
        float v = 0.f;
        if (o < NOUT) {
            if (f < 144) {
                int p = f >> 4, c = f & 15;
                float s = 0.f;
                if (o < 9) {
                    for (int cm = 0; cm < 16; ++cm)
                        s += mask_w[o * 64 + cm] * mask_pconv_w[(cm * 16 + c) * 9 + p];
                } else {
                    int oo = o - 9, i = oo / 18, j = oo % 18;
                    for (int cm = 0; cm < 16; ++cm)
                        s += off_w[(i * 18 + j) * 64 + cm] * off_pconv_w[((i * 16 + cm) * 16 + c) * 9 + p];
                }
                v = s;
            } else {
                int c = f - 144;
                if (o < 9) v = mask_w[o * 64 + 16 + c];
                else { int oo = o - 9, i = oo / 18, j = oo % 18; v = off_w[(i * 18 + j) * 64 + 16 + c]; }
            }
        }
        WtP[id] = v;
    } else if (id < NFEAT * WROW + NOUT) {
        int o = id - NFEAT * WROW;
        float v;
        if (o < 9) v = mask_b[o];
        else {
            int oo = o - 9, i = oo / 18, j = oo % 18;
            v = off_b[i * 18 + j] + PTS[j] * (float)(2 * i + 1);
        }
        biasP[o] = v;
    }
}

// ---------------------------------------------------------------------------
// Conv (round-18 verbatim, the measured best): SGPR weights (wave-uniform
// slice base via readfirstlane -> scalar pipe), c-loop unroll 4, no LDS.
// ---------------------------------------------------------------------------
__global__ __launch_bounds__(256) void conv_sgpr(
    const float* __restrict__ x, const float* __restrict__ WtP,
    const float* __restrict__ biasP,
    float* __restrict__ mask_ws, float* __restrict__ off_ws)
{
    int tid = threadIdx.x;
    int lane = tid & 63;
    int bid = blockIdx.x;            // 2048
    int b = bid >> 10;
    int pix = (bid & 1023) * 64 + lane;
    int h = pix >> 8, w = pix & 255;

    int ob0 = __builtin_amdgcn_readfirstlane((tid >> 6) * 20);

    float acc[21];
#pragma unroll
    for (int j = 0; j < 21; ++j) acc[j] = biasP[ob0 + j];

    const float* xb = x + (size_t)b * 64 * HW;

#pragma unroll 1
    for (int p = 0; p < 9; ++p) {
        int hh = h + p / 3 - 1;
        int dx = p % 3 - 1;
        int ww = w + dx;
        bool valid = ((unsigned)hh < 256u) && ((unsigned)ww < 256u);
        int poff = hh * 256 + ww;
#pragma unroll 4
        for (int c = 0; c < 16; ++c) {
            float xv = valid ? xb[c * HW + poff] : 0.f;
            const float* wr = WtP + (p * 16 + c) * WROW + ob0;
#pragma unroll
            for (int j = 0; j < 21; ++j) acc[j] = fmaf(xv, wr[j], acc[j]);
        }
    }
#pragma unroll 4
    for (int c = 0; c < 48; ++c) {
        float xv = xb[(16 + c) * HW + pix];
        const float* wr = WtP + (144 + c) * WROW + ob0;
#pragma unroll
        for (int j = 0; j < 21; ++j) acc[j] = fmaf(xv, wr[j], acc[j]);
    }

#pragma unroll
    for (int j = 0; j < 21; ++j) {
        int o = ob0 + j;
        float* pl;
        if (o < 9) pl = mask_ws + (size_t)(b * 9 + o) * HW + pix;
        else       pl = off_ws  + (size_t)(b * 72 + (o - 9)) * HW + pix;
        *pl = acc[j];
    }
}

// ---------------------------------------------------------------------------
// Transpose y -> c4-major interleaved Tc[z][pix][c4:{t0 4ch, t1 4ch}] bf16.
// One 16B gather row per (pixel, c4) serves BOTH tensors' 4 channels.
// ---------------------------------------------------------------------------
__global__ __launch_bounds__(256) void transpose_y_c(
    const float* __restrict__ y, ushort_t* __restrict__ Tc)
{
    int bid = blockIdx.x;            // 2048
    int z = bid & 7, pr = bid >> 3;
    int pix = pr * 256 + threadIdx.x;
    int xb = z >> 2, i = z & 3;

    const float* p0 = y + (size_t)(xb * 64 + i * 16) * HW + pix;
    const float* p1 = y + (size_t)((xb + 2) * 64 + i * 16) * HW + pix;

    ushort_t v0[16], v1[16];
#pragma unroll
    for (int c = 0; c < 16; ++c) v0[c] = f2bf(p0[(size_t)c * HW]);
#pragma unroll
    for (int c = 0; c < 16; ++c) v1[c] = f2bf(p1[(size_t)c * HW]);

    uint4* dst = (uint4*)(Tc + ((size_t)z * HW + pix) * 32);
#pragma unroll
    for (int j = 0; j < 4; ++j) {
        ushort_t row[8] = {v0[4*j], v0[4*j+1], v0[4*j+2], v0[4*j+3],
                           v1[4*j], v1[4*j+1], v1[4*j+2], v1[4*j+3]};
        dst[j] = *(const uint4*)row;
    }
}

// ---------------------------------------------------------------------------
// Warp kernel (round-18 verbatim, the measured best): k in the grid (TLP
// latency hiding; one short chain per thread), NT stores (keep the 604MB
// write stream OUT of L2 so the 4MB/XCD Tc slices stay resident — r19 A/B
// showed plain stores cost +63us), z in low bits for XCD pinning.
// ---------------------------------------------------------------------------
__global__ __launch_bounds__(256) void warp_k(
    const ushort_t* __restrict__ Tc,    // (8,HW,32) bf16 c4-major
    const float* __restrict__ mask_ws,  // (2,9,HW)
    const float* __restrict__ off_ws,   // (2,72,HW)
    float* __restrict__ out)            // (4,64,9,HW)
{
    int bid = blockIdx.x;
    int z  = bid & 7;
    int wc = (bid >> 3) & 3;
    int h  = (bid >> 5) & 255;
    int k  = bid >> 13;              // 0..8
    int c4 = threadIdx.x & 3;
    int pl = threadIdx.x >> 2;       // 0..63
    int w  = wc * 64 + pl;
    int pix = h * 256 + w;
    int xb = z >> 2, i = z & 3;

    const ushort_t* Tt = Tc + (size_t)z * HW * 32;

    float ox = off_ws[(size_t)(z * 18 + 2 * k) * HW + pix];
    float oy = off_ws[(size_t)(z * 18 + 2 * k + 1) * HW + pix];
    float m  = mask_ws[(size_t)(xb * 9 + k) * HW + pix];

    float px = fminf(fmaxf((float)w + ox, 0.f), 255.f);
    float py = fminf(fmaxf((float)h + oy, 0.f), 255.f);
    float x0f = floorf(px), y0f = floorf(py);
    float wx = px - x0f, wy = py - y0f;
    int x0 = (int)x0f, y0 = (int)y0f;
    int x1 = min(x0 + 1, 255), y1 = min(y0 + 1, 255);

    float w00 = (1.f - wx) * (1.f - wy) * m;
    float w01 = wx * (1.f - wy) * m;
    float w10 = (1.f - wx) * wy * m;
    float w11 = wx * wy * m;

    int sec = c4 * 8;
    uint4 A = *(const uint4*)(Tt + (size_t)(y0 * 256 + x0) * 32 + sec);
    uint4 B = *(const uint4*)(Tt + (size_t)(y0 * 256 + x1) * 32 + sec);
    uint4 C = *(const uint4*)(Tt + (size_t)(y1 * 256 + x0) * 32 + sec);
    uint4 D = *(const uint4*)(Tt + (size_t)(y1 * 256 + x1) * 32 + sec);

    float s0 = w00 * bflo(A.x), s1 = w00 * bfhi(A.x);
    float s2 = w00 * bflo(A.y), s3 = w00 * bfhi(A.y);
    float u0 = w00 * bflo(A.z), u1 = w00 * bfhi(A.z);
    float u2 = w00 * bflo(A.w), u3 = w00 * bfhi(A.w);

    s0 = fmaf(w01, bflo(B.x), s0); s1 = fmaf(w01, bfhi(B.x), s1);
    s2 = fmaf(w01, bflo(B.y), s2); s3 = fmaf(w01, bfhi(B.y), s3);
    u0 = fmaf(w01, bflo(B.z), u0); u1 = fmaf(w01, bfhi(B.z), u1);
    u2 = fmaf(w01, bflo(B.w), u2); u3 = fmaf(w01, bfhi(B.w), u3);

    s0 = fmaf(w10, bflo(C.x), s0); s1 = fmaf(w10, bfhi(C.x), s1);
    s2 = fmaf(w10, bflo(C.y), s2); s3 = fmaf(w10, bfhi(C.y), s3);
    u0 = fmaf(w10, bflo(C.z), u0); u1 = fmaf(w10, bfhi(C.z), u1);
    u2 = fmaf(w10, bflo(C.w), u2); u3 = fmaf(w10, bfhi(C.w), u3);

    s0 = fmaf(w11, bflo(D.x), s0); s1 = fmaf(w11, bfhi(D.x), s1);
    s2 = fmaf(w11, bflo(D.y), s2); s3 = fmaf(w11, bfhi(D.y), s3);
    u0 = fmaf(w11, bflo(D.z), u0); u1 = fmaf(w11, bfhi(D.z), u1);
    u2 = fmaf(w11, bflo(D.w), u2); u3 = fmaf(w11, bfhi(D.w), u3);

    float* p0 = out + ((size_t)(xb * 64 + i * 16 + c4 * 4)) * 9 * HW
              + (size_t)k * HW + pix;
    __builtin_nontemporal_store(s0, p0);
    __builtin_nontemporal_store(s1, p0 + (size_t)9 * HW);
    __builtin_nontemporal_store(s2, p0 + (size_t)18 * HW);
    __builtin_nontemporal_store(s3, p0 + (size_t)27 * HW);
    float* p1 = p0 + (size_t)128 * 9 * HW;
    __builtin_nontemporal_store(u0, p1);
    __builtin_nontemporal_store(u1, p1 + (size_t)9 * HW);
    __builtin_nontemporal_store(u2, p1 + (size_t)18 * HW);
    __builtin_nontemporal_store(u3, p1 + (size_t)27 * HW);
}

// ---------------------------------------------------------------------------
// Fallback path (ws too small): conv to planes + direct warp from y.
// ---------------------------------------------------------------------------
__global__ __launch_bounds__(256) void warp_apply(
    const float* __restrict__ y,
    const float* __restrict__ mask_ws,
    const float* __restrict__ off_ws,
    float* __restrict__ out)
{
    int w = threadIdx.x;
    int h = blockIdx.x;
    int k = blockIdx.y;
    int z = blockIdx.z;
    int xb = z >> 2, i = z & 3;
    int pix = h * 256 + w;

    float ox = off_ws[(size_t)(z * 18 + 2 * k) * HW + pix];
    float oy = off_ws[(size_t)(z * 18 + 2 * k + 1) * HW + pix];
    float m  = mask_ws[(size_t)(xb * 9 + k) * HW + pix];

    float px = fminf(fmaxf((float)w + ox, 0.f), 255.f);
    float py = fminf(fmaxf((float)h + oy, 0.f), 255.f);
    float x0f = floorf(px), y0f = floorf(py);
    float wx = px - x0f, wy = py - y0f;
    int x0 = (int)x0f, y0 = (int)y0f;
    int x1 = min(x0 + 1, 255), y1 = min(y0 + 1, 255);

    float w00 = (1.f - wx) * (1.f - wy) * m;
    float w01 = wx * (1.f - wy) * m;
    float w10 = (1.f - wx) * wy * m;
    float w11 = wx * wy * m;

    int o00 = y0 * 256 + x0, o01 = y0 * 256 + x1;
    int o10 = y1 * 256 + x0, o11 = y1 * 256 + x1;

    const float* p1 = y + (size_t)(xb * 64 + i * 16) * HW;
    const float* p2 = y + (size_t)((xb + 2) * 64 + i * 16) * HW;
    float* out1 = out + ((size_t)(xb * 64 + i * 16) * 9 + k) * HW + pix;
    float* out2 = out + ((size_t)((xb + 2) * 64 + i * 16) * 9 + k) * HW + pix;

#pragma unroll
    for (int c = 0; c < 16; ++c) {
        const float* q = p1 + (size_t)c * HW;
        float v = w00 * q[o00] + w01 * q[o01] + w10 * q[o10] + w11 * q[o11];
        out1[(size_t)c * 9 * HW] = v;
        q = p2 + (size_t)c * HW;
        v = w00 * q[o00] + w01 * q[o01] + w10 * q[o10] + w11 * q[o11];
        out2[(size_t)c * 9 * HW] = v;
    }
}

// ---------------------------------------------------------------------------
extern "C" void kernel_launch(void* const* d_in, const int* in_sizes, int n_in,
                              void* d_out, int out_size, void* d_ws, size_t ws_size,
                              hipStream_t stream) {
    const float* x            = (const float*)d_in[0];
    const float* y            = (const float*)d_in[1];
    const float* off_pconv_w  = (const float*)d_in[2];
    const float* off_w        = (const float*)d_in[3];
    const float* off_b        = (const float*)d_in[4];
    const float* mask_pconv_w = (const float*)d_in[5];
    const float* mask_w       = (const float*)d_in[6];
    const float* mask_b       = (const float*)d_in[7];
    float* out = (float*)d_out;

    // ws: [WtP 192*84 f32 + biasP: 64KB] [mask (2,9,HW) f32: 4.7MB]
    //     [off (2,72,HW) f32: 37.7MB] [Tc (8,HW,32) bf16: 33.6MB]  ~76MB
    float* WtP     = (float*)d_ws;
    float* biasP   = WtP + NFEAT * WROW;
    float* mask_ws = (float*)((char*)d_ws + 65536);
    float* off_ws  = mask_ws + (size_t)2 * 9 * HW;
    ushort_t* Tc   = (ushort_t*)(off_ws + (size_t)2 * 72 * HW);
    size_t need = 65536 + (size_t)2 * 9 * HW * 4 + (size_t)2 * 72 * HW * 4
                + (size_t)8 * HW * 32 * 2;

    setup_weights<<<64, 256, 0, stream>>>(off_pconv_w, off_w, off_b,
                                          mask_pconv_w, mask_w, mask_b, WtP, biasP);

    conv_sgpr<<<2048, 256, 0, stream>>>(x, WtP, biasP, mask_ws, off_ws);

    if (ws_size >= need) {
        transpose_y_c<<<2048, 256, 0, stream>>>(y, Tc);
        warp_k<<<73728, 256, 0, stream>>>(Tc, mask_ws, off_ws, out);
    } else {
        dim3 g2(256, 9, 8);
        warp_apply<<<g2, 256, 0, stream>>>(y, mask_ws, off_ws, out);
    }
}